// Round 6
// baseline (13857.787 us; speedup 1.0000x reference)
//
#include <hip/hip_runtime.h>

typedef _Float16 f16;
typedef _Float16 f16x2 __attribute__((ext_vector_type(2)));
typedef _Float16 f16x4 __attribute__((ext_vector_type(4)));
typedef _Float16 f16x8 __attribute__((ext_vector_type(8)));
typedef float f32x4 __attribute__((ext_vector_type(4)));

#define B_ 64
#define S_ 1024
#define I_ 64
#define H_ 256
#define G_ 1024      // 4*H
#define M_ 65536     // B*S

// ======================= Threefry-2x32-20 (JAX) =======================
__device__ __forceinline__ unsigned rotl32(unsigned x, int r){ return (x<<r)|(x>>(32-r)); }

__device__ __forceinline__ void threefry(unsigned k0, unsigned k1, unsigned& x0, unsigned& x1){
  unsigned k2 = k0 ^ k1 ^ 0x1BD11BDAu;
  x0 += k0; x1 += k1;
  x0 += x1; x1 = rotl32(x1,13); x1 ^= x0;
  x0 += x1; x1 = rotl32(x1,15); x1 ^= x0;
  x0 += x1; x1 = rotl32(x1,26); x1 ^= x0;
  x0 += x1; x1 = rotl32(x1, 6); x1 ^= x0;
  x0 += k1; x1 += k2 + 1u;
  x0 += x1; x1 = rotl32(x1,17); x1 ^= x0;
  x0 += x1; x1 = rotl32(x1,29); x1 ^= x0;
  x0 += x1; x1 = rotl32(x1,16); x1 ^= x0;
  x0 += x1; x1 = rotl32(x1,24); x1 ^= x0;
  x0 += k2; x1 += k0 + 2u;
  x0 += x1; x1 = rotl32(x1,13); x1 ^= x0;
  x0 += x1; x1 = rotl32(x1,15); x1 ^= x0;
  x0 += x1; x1 = rotl32(x1,26); x1 ^= x0;
  x0 += x1; x1 = rotl32(x1, 6); x1 ^= x0;
  x0 += k0; x1 += k1 + 3u;
  x0 += x1; x1 = rotl32(x1,17); x1 ^= x0;
  x0 += x1; x1 = rotl32(x1,29); x1 ^= x0;
  x0 += x1; x1 = rotl32(x1,16); x1 ^= x0;
  x0 += x1; x1 = rotl32(x1,24); x1 ^= x0;
  x0 += k1; x1 += k2 + 4u;
  x0 += x1; x1 = rotl32(x1,13); x1 ^= x0;
  x0 += x1; x1 = rotl32(x1,15); x1 ^= x0;
  x0 += x1; x1 = rotl32(x1,26); x1 ^= x0;
  x0 += x1; x1 = rotl32(x1, 6); x1 ^= x0;
  x0 += k2; x1 += k0 + 5u;
}

// XLA ErfInv32 (Giles)
__device__ __forceinline__ float erfinv_f(float x){
  float w = -log1pf(-x*x);
  float p;
  if (w < 5.f){
    w -= 2.5f;
    p = 2.81022636e-08f;
    p = fmaf(p,w, 3.43273939e-07f);
    p = fmaf(p,w,-3.5233877e-06f);
    p = fmaf(p,w,-4.39150654e-06f);
    p = fmaf(p,w, 0.00021858087f);
    p = fmaf(p,w,-0.00125372503f);
    p = fmaf(p,w,-0.00417768164f);
    p = fmaf(p,w, 0.246640727f);
    p = fmaf(p,w, 1.50140941f);
  } else {
    w = sqrtf(w) - 3.f;
    p = -0.000200214257f;
    p = fmaf(p,w, 0.000100950558f);
    p = fmaf(p,w, 0.00134934322f);
    p = fmaf(p,w,-0.00367342844f);
    p = fmaf(p,w, 0.00573950773f);
    p = fmaf(p,w,-0.0076224613f);
    p = fmaf(p,w, 0.00943887047f);
    p = fmaf(p,w, 1.00167406f);
    p = fmaf(p,w, 2.83297682f);
  }
  return p*x;
}

__device__ __forceinline__ float jax_normal_from_bits(unsigned bits){
  unsigned fb = (bits >> 9) | 0x3f800000u;
  float f = __uint_as_float(fb) - 1.0f;                 // [0,1)
  const float lo = -0.9999999403953552f;                // nextafter(-1,0)
  float u = fmaf(f, 2.0f, lo);
  u = fmaxf(lo, u);
  return 1.4142135623730951f * erfinv_f(u);
}

// psiP[j] = pack(half(cos(theta+tn)), half(sin(phi+pn))), j = k*256+n
__global__ __launch_bounds__(256) void prep_psi(const float* __restrict__ theta,
                                                const float* __restrict__ phi,
                                                unsigned* __restrict__ psiP){
  int j = blockIdx.x*256 + threadIdx.x;  // 0..16383
  unsigned a0=0u, a1=0u; threefry(0u,42u,a0,a1);   // k1 (theta noise)
  unsigned b0=0u, b1=1u; threefry(0u,42u,b0,b1);   // k2 (phi noise)
  unsigned t0=0u, t1=(unsigned)j; threefry(a0,a1,t0,t1);
  unsigned p0=0u, p1=(unsigned)j; threefry(b0,b1,p0,p1);
  float tn = 0.01f * jax_normal_from_bits(t0^t1);
  float pn = 0.01f * jax_normal_from_bits(p0^p1);
  float cr = cosf(theta[j] + tn);
  float ci = sinf(phi[j]   + pn);
  f16x2 pk; pk.x = (f16)cr; pk.y = (f16)ci;
  psiP[j] = __builtin_bit_cast(unsigned, pk);
}

// ======================= MFMA fragment packing =======================
// gate(w,nt,lr) = (nt>>1)*256 + w*32 + (nt&1)*16 + lr
//   -> each wave w owns, for every gate type {i,f,g,o}, elements [w*32, w*32+32),
//      so i/f/g/o for one (batch, element) land in the SAME lane after MFMA.
// B-frag(w,nt,ks): lane l holds W[gate(w,nt,l&15)][ks*32 + (l>>4)*8 .. +8) (f16x8).
// Class split per wave: ks0..3 -> VGPR (32 frags), ks4..5 -> LDS (16), ks6..7 -> L2-stream (16).
__global__ __launch_bounds__(256) void pack_w16(const float* __restrict__ W,  // [2][1024][256]
                                                uint4* __restrict__ dstV,     // [2][8][32][64]
                                                uint4* __restrict__ dstL,     // [2][128][64]
                                                uint4* __restrict__ dstG){    // [2][8][16][64]
  int idx  = blockIdx.x*256 + threadIdx.x;   // 0..65535
  int lane = idx & 63;
  int ks   = (idx>>6) & 7;
  int nt   = (idx>>9) & 7;
  int w    = (idx>>12) & 7;
  int l    = idx>>15;
  int gate = (nt>>1)*256 + w*32 + (nt&1)*16 + (lane&15);
  int k0   = ks*32 + (lane>>4)*8;
  const float* src = W + ((size_t)(l*1024 + gate))*256 + k0;
  f16x8 v;
  #pragma unroll
  for (int e=0;e<8;++e) v[e] = (f16)src[e];
  uint4 pv = __builtin_bit_cast(uint4, v);
  if (ks < 4)      dstV[(((size_t)l*8 + w)*32 + (ks*8 + nt))*64 + lane] = pv;
  else if (ks < 6) dstL[((size_t)l*128 + w*16 + (ks-4)*8 + nt)*64 + lane] = pv;
  else             dstG[(((size_t)l*8 + w)*16 + ((ks-6)*8 + nt))*64 + lane] = pv;
}

__global__ __launch_bounds__(256) void bias_k(const float* __restrict__ bih,
                                              const float* __restrict__ bhh,
                                              float* __restrict__ biasS){
  int idx = blockIdx.x*256 + threadIdx.x;   // 0..2047
  biasS[idx] = bih[idx] + bhh[idx];
}

// ======================= quantum phase =======================
__global__ __launch_bounds__(256) void quantum_k(const float* __restrict__ x,
                                                 const unsigned* __restrict__ psiP,
                                                 f16* __restrict__ yq){
  __shared__ float xs[64];
  int m = blockIdx.x;
  int n = threadIdx.x;
  if (n < 64) xs[n] = x[(size_t)m*64 + n];
  __syncthreads();
  float ar=0.f, ai=0.f;
  #pragma unroll 8
  for (int k=0;k<64;k++){
    unsigned p = psiP[k*256 + n];
    f16x2 pk = __builtin_bit_cast(f16x2, p);
    float xv = xs[k];
    ar = fmaf(xv, (float)pk.x, ar);
    ai = fmaf(xv, (float)pk.y, ai);
  }
  yq[(size_t)m*256 + n] = (f16)sqrtf(ar*ar + ai*ai);
}

__device__ __forceinline__ float sigm_f(float x){
  x = fminf(fmaxf(x,-30.f),30.f);
  return 1.f/(1.f + __expf(-x));
}
__device__ __forceinline__ float tanh_f(float x){
  x = fminf(fmaxf(x,-15.f),15.f);
  float e = __expf(-2.f*x);
  return (1.f-e)/(1.f+e);
}

__device__ __forceinline__ f32x4 mfma16(uint4 a, uint4 b, f32x4 c){
  return __builtin_amdgcn_mfma_f32_16x16x32_f16(
      __builtin_bit_cast(f16x8, a), __builtin_bit_cast(f16x8, b), c, 0, 0, 0);
}

// ======================= pre-activation GEMM (group-structured) =======================
// Block: group g (16 batches), 32 timesteps. 8 waves; wave w -> gates gate(w,nt,lr).
// A tile = X[g*16 .. g*16+15][t][256] (M=batch), B = W_ih frags, C written in
// EXACTLY lstm16's pre-fragment order:
//   f16 idx = (((g*1024+t)*8 + w)*8 + nt)*256 + lane*4 + j,
//   holding pre[b = (lane>>4)*4 + j][gate(w,nt,lane&15)] + bias.
__global__ __launch_bounds__(512,2)
void pre_gemm16(const f16* __restrict__ X,     // [64][1024][256] rows b*1024+t
                const uint4* __restrict__ WV,  // this layer: [8][32][64]
                const uint4* __restrict__ WL,  // this layer: [128][64]
                const uint4* __restrict__ WG,  // this layer: [8][16][64]
                const float* __restrict__ bias,// this layer: [1024]
                f16* __restrict__ outF)
{
  __shared__ __align__(16) uint4 wlds[8192];   // 128 KB: ks4,5 frags
  const int bid = blockIdx.x;                  // 0..127
  const int g   = bid & 3;
  const int t0  = (bid>>2)*32;
  const int tid = threadIdx.x;
  const int w = tid>>6, lane = tid&63;
  const int lr = lane&15, q = lane>>4;

  uint4 wv[32];
  #pragma unroll
  for (int i=0;i<32;++i) wv[i] = WV[(size_t)(w*32+i)*64 + lane];
  #pragma unroll
  for (int i=0;i<16;++i) wlds[tid + i*512] = WL[tid + i*512];
  __syncthreads();

  float bs[8];
  #pragma unroll
  for (int nt=0;nt<8;++nt) bs[nt] = bias[(nt>>1)*256 + w*32 + (nt&1)*16 + lr];

  const f16*   xrow = X + ((size_t)(g*16 + lr))*1024*256 + q*8;
  const uint4* wgb  = WG + (size_t)(w*16)*64 + lane;

  for (int tt=0; tt<32; ++tt){
    const int t = t0 + tt;
    uint4 af[8];
    #pragma unroll
    for (int ks=0;ks<8;++ks) af[ks] = *(const uint4*)(xrow + (size_t)t*256 + ks*32);
    uint4 bg6[8];
    #pragma unroll
    for (int i=0;i<8;++i) bg6[i] = wgb[i*64];
    uint4 bg7[8];
    f32x4 acc[8];
    #pragma unroll
    for (int i=0;i<8;++i) acc[i] = (f32x4){0.f,0.f,0.f,0.f};

    #pragma unroll
    for (int ks=0; ks<8; ++ks){
      if (ks == 5){
        #pragma unroll
        for (int i=0;i<8;++i) bg7[i] = wgb[(8+i)*64];
      }
      #pragma unroll
      for (int nt=0; nt<8; ++nt){
        uint4 bf;
        if (ks < 4)       bf = wv[ks*8 + nt];
        else if (ks < 6)  bf = wlds[(w*16 + (ks-4)*8 + nt)*64 + lane];
        else if (ks == 6) bf = bg6[nt];
        else              bf = bg7[nt];
        acc[nt] = mfma16(af[ks], bf, acc[nt]);
      }
    }
    f16* outp = outF + (((size_t)(g*1024 + t)*8 + w)*8)*256 + lane*4;
    #pragma unroll
    for (int nt=0; nt<8; ++nt){
      f16x4 o;
      #pragma unroll
      for (int j=0;j<4;++j) o[j] = (f16)(acc[nt][j] + bs[nt]);
      *(f16x4*)(outp + nt*256) = o;
    }
  }
}

// ======================= in-CU MFMA LSTM (16 batches / CU) =======================
// 4 blocks (one batch-group each), 512 threads = 8 waves (2/SIMD, 256-VGPR budget).
// Per step: A = h(t-1)[16][256] from double-buffered XOR-swizzled LDS; 64 MFMA/wave
// (M=16 batches, N=128 gates, K=256); i/f/g/o for each (b,e) land in-lane (gate
// tiling above) -> c/h update fully in-lane, ONE barrier per step.
template<int WRITE_ALL>
__global__ __launch_bounds__(512,2)
void lstm16(const f16* __restrict__ preF,     // this layer, frag order
            const uint4* __restrict__ WV,     // this layer: [8][32][64]
            const uint4* __restrict__ WL,     // this layer: [128][64]
            const uint4* __restrict__ WG,     // this layer: [8][16][64]
            f16* __restrict__ h1,             // [64][1024][256] if WRITE_ALL
            f16* __restrict__ hfin)           // [64][256]
{
  __shared__ __align__(16) uint4 wlds[8192];  // 128 KB: ks4,5 frags
  __shared__ __align__(16) char  hbuf[16384]; // 2 x 8KB h double buffer (swizzled)
  const int g   = blockIdx.x;
  const int tid = threadIdx.x;
  const int w = tid>>6, lane = tid&63;
  const int lr = lane&15, q = lane>>4;

  uint4 wv[32];
  #pragma unroll
  for (int i=0;i<32;++i) wv[i] = WV[(size_t)(w*32+i)*64 + lane];
  #pragma unroll
  for (int i=0;i<16;++i) wlds[tid + i*512] = WL[tid + i*512];
  #pragma unroll
  for (int i=0;i<2;++i) ((uint4*)hbuf)[tid + i*512] = make_uint4(0u,0u,0u,0u);
  __syncthreads();

  // A-read swizzle pieces (row b = lr): addr = ((lr*512 + q*16 + ks*64) ^ ((lr&7)<<4)) + buf
  const int swb = lr*512 + q*16;
  const int sx  = (lr&7)<<4;
  // pre fragment base: f16 idx = ((g*1024+t)*64 + w*8 + nt)*256 + lane*4
  const f16*   pbase = preF + ((size_t)g*1024*64 + w*8)*256 + lane*4;
  const uint4* wgb   = WG + (size_t)(w*16)*64 + lane;

  float c_[8];
  #pragma unroll
  for (int i=0;i<8;++i) c_[i] = 0.f;

  f16* h1b = h1 + (size_t)(g*16)*1024*256;   // only dereferenced if WRITE_ALL

  for (int t=0; t<1024; ++t){
    const int rb = ((t^1)&1)*8192;   // read h(t-1); t=0 reads buf1 (zeroed)
    const int wb = (t&1)*8192;       // write h(t)

    // pre for this step (used after MFMA; HBM latency hides under compute)
    const f16* pt = pbase + (size_t)t*16384;
    f16x4 pc[8];
    #pragma unroll
    for (int nt=0;nt<8;++nt) pc[nt] = *(const f16x4*)(pt + nt*256);

    uint4 bg6[8];
    #pragma unroll
    for (int i=0;i<8;++i) bg6[i] = wgb[i*64];
    uint4 bg7[8];

    f32x4 acc[8];
    #pragma unroll
    for (int i=0;i<8;++i) acc[i] = (f32x4){0.f,0.f,0.f,0.f};

    #pragma unroll
    for (int ks=0; ks<8; ++ks){
      if (ks == 5){
        #pragma unroll
        for (int i=0;i<8;++i) bg7[i] = wgb[(8+i)*64];
      }
      const uint4 a = *(const uint4*)(hbuf + (((swb + ks*64) ^ sx) + rb));
      #pragma unroll
      for (int nt=0; nt<8; ++nt){
        uint4 bf;
        if (ks < 4)       bf = wv[ks*8 + nt];
        else if (ks < 6)  bf = wlds[(w*16 + (ks-4)*8 + nt)*64 + lane];
        else if (ks == 6) bf = bg6[nt];
        else              bf = bg7[nt];
        acc[nt] = mfma16(a, bf, acc[nt]);
      }
    }

    // in-lane activation + c/h for 8 (b,e) pairs:
    //   b = q*4 + j, e = w*32 + s*16 + lr
    #pragma unroll
    for (int s=0; s<2; ++s){
      #pragma unroll
      for (int j=0; j<4; ++j){
        const float i_ = sigm_f(acc[0+s][j] + (float)pc[0+s][j]);
        const float f_ = sigm_f(acc[2+s][j] + (float)pc[2+s][j]);
        const float g_ = tanh_f(acc[4+s][j] + (float)pc[4+s][j]);
        const float o_ = sigm_f(acc[6+s][j] + (float)pc[6+s][j]);
        const float cn = fmaf(f_, c_[s*4+j], i_*g_);
        c_[s*4+j] = cn;
        const float hh = o_ * tanh_f(cn);
        const f16 hf = (f16)hh;
        const int b = q*4 + j;
        const int e = w*32 + s*16 + lr;
        *(f16*)(hbuf + ((((b*512 + e*2) ^ ((b&7)<<4))) + wb)) = hf;
        if (WRITE_ALL) h1b[((size_t)b*1024 + t)*256 + e] = hf;
        else if (t == 1023) hfin[(g*16 + b)*256 + e] = hf;
      }
    }
    __syncthreads();
  }
}

// ======================= final FC =======================
__global__ __launch_bounds__(64) void fc_k(const f16* __restrict__ hfin,
                                           const float* __restrict__ Wfc,
                                           const float* __restrict__ bfc,
                                           float* __restrict__ out){
  int b = blockIdx.x, k = threadIdx.x;
  float a = 0.f;
  #pragma unroll
  for (int j=0;j<4;j++){
    int idx = k + 64*j;
    a += (float)hfin[b*256 + idx] * Wfc[idx];
  }
  #pragma unroll
  for (int off=32; off; off>>=1) a += __shfl_down(a, off);
  if (k==0) out[b] = a + bfc[0];
}

// ======================= launch =======================
extern "C" void kernel_launch(void* const* d_in, const int* in_sizes, int n_in,
                              void* d_out, int out_size, void* d_ws, size_t ws_size,
                              hipStream_t stream) {
  const float* x     = (const float*)d_in[0];
  const float* theta = (const float*)d_in[1];
  const float* phi   = (const float*)d_in[2];
  const float* Wih   = (const float*)d_in[3];
  const float* Whh   = (const float*)d_in[4];
  const float* bih   = (const float*)d_in[5];
  const float* bhh   = (const float*)d_in[6];
  const float* Wfc   = (const float*)d_in[7];
  const float* bfc   = (const float*)d_in[8];
  float* out = (float*)d_out;

  char* ws = (char*)d_ws;
  size_t off = 0;
  auto take = [&](size_t bytes){ size_t r = off; off += (bytes + 255) & ~(size_t)255; return r; };
  // ~203.5 MB total (same proven footprint as rounds 0/4).
  f16*      preF  = (f16*)     (ws + take((size_t)M_*1024*2));   // 134 MB, frag order, reused L1/L2
  f16*      yq    = (f16*)     (ws + take((size_t)M_*256*2));    // 33.5 MB
  f16*      h1    = (f16*)     (ws + take((size_t)M_*256*2));    // 33.5 MB
  unsigned* psiP  = (unsigned*)(ws + take((size_t)16384*4));
  uint4*    WhV   = (uint4*)   (ws + take((size_t)2*16384*16));  // 512 KB
  uint4*    WhL   = (uint4*)   (ws + take((size_t)2*8192*16));   // 256 KB
  uint4*    WhG   = (uint4*)   (ws + take((size_t)2*8192*16));   // 256 KB
  uint4*    WiV   = (uint4*)   (ws + take((size_t)2*16384*16));  // 512 KB
  uint4*    WiL   = (uint4*)   (ws + take((size_t)2*8192*16));   // 256 KB
  uint4*    WiG   = (uint4*)   (ws + take((size_t)2*8192*16));   // 256 KB
  float*    biasS = (float*)   (ws + take((size_t)2048*4));
  f16*      hfin  = (f16*)     (ws + take((size_t)64*256*2));

  prep_psi <<<64,   256, 0, stream>>>(theta, phi, psiP);
  pack_w16 <<<256,  256, 0, stream>>>(Whh, WhV, WhL, WhG);
  pack_w16 <<<256,  256, 0, stream>>>(Wih, WiV, WiL, WiG);
  bias_k   <<<8,    256, 0, stream>>>(bih, bhh, biasS);
  quantum_k<<<65536,256, 0, stream>>>(x, psiP, yq);

  // layer 1
  pre_gemm16<<<128, 512, 0, stream>>>(yq, WiV, WiL, WiG, biasS, preF);
  lstm16<1> <<<4,   512, 0, stream>>>(preF, WhV, WhL, WhG, h1, hfin);
  // layer 2
  pre_gemm16<<<128, 512, 0, stream>>>(h1, WiV + 16384, WiL + 8192, WiG + 8192,
                                      biasS + 1024, preF);
  lstm16<0> <<<4,   512, 0, stream>>>(preF, WhV + 16384, WhL + 8192, WhG + 8192,
                                      h1, hfin);

  fc_k <<<64, 64, 0, stream>>>(hfin, Wfc, bfc, out);
}

// Round 7
// 2602.541 us; speedup vs baseline: 5.3247x; 5.3247x over previous
//
#include <hip/hip_runtime.h>

typedef _Float16 f16;
typedef _Float16 f16x2 __attribute__((ext_vector_type(2)));
typedef _Float16 f16x8 __attribute__((ext_vector_type(8)));
typedef float f32x4 __attribute__((ext_vector_type(4)));

#define B_ 64
#define S_ 1024
#define I_ 64
#define H_ 256
#define G_ 1024      // 4*H
#define M_ 65536     // B*S

// ======================= Threefry-2x32-20 (JAX) =======================
__device__ __forceinline__ unsigned rotl32(unsigned x, int r){ return (x<<r)|(x>>(32-r)); }

__device__ __forceinline__ void threefry(unsigned k0, unsigned k1, unsigned& x0, unsigned& x1){
  unsigned k2 = k0 ^ k1 ^ 0x1BD11BDAu;
  x0 += k0; x1 += k1;
  x0 += x1; x1 = rotl32(x1,13); x1 ^= x0;
  x0 += x1; x1 = rotl32(x1,15); x1 ^= x0;
  x0 += x1; x1 = rotl32(x1,26); x1 ^= x0;
  x0 += x1; x1 = rotl32(x1, 6); x1 ^= x0;
  x0 += k1; x1 += k2 + 1u;
  x0 += x1; x1 = rotl32(x1,17); x1 ^= x0;
  x0 += x1; x1 = rotl32(x1,29); x1 ^= x0;
  x0 += x1; x1 = rotl32(x1,16); x1 ^= x0;
  x0 += x1; x1 = rotl32(x1,24); x1 ^= x0;
  x0 += k2; x1 += k0 + 2u;
  x0 += x1; x1 = rotl32(x1,13); x1 ^= x0;
  x0 += x1; x1 = rotl32(x1,15); x1 ^= x0;
  x0 += x1; x1 = rotl32(x1,26); x1 ^= x0;
  x0 += x1; x1 = rotl32(x1, 6); x1 ^= x0;
  x0 += k0; x1 += k1 + 3u;
  x0 += x1; x1 = rotl32(x1,17); x1 ^= x0;
  x0 += x1; x1 = rotl32(x1,29); x1 ^= x0;
  x0 += x1; x1 = rotl32(x1,16); x1 ^= x0;
  x0 += x1; x1 = rotl32(x1,24); x1 ^= x0;
  x0 += k1; x1 += k2 + 4u;
  x0 += x1; x1 = rotl32(x1,13); x1 ^= x0;
  x0 += x1; x1 = rotl32(x1,15); x1 ^= x0;
  x0 += x1; x1 = rotl32(x1,26); x1 ^= x0;
  x0 += x1; x1 = rotl32(x1, 6); x1 ^= x0;
  x0 += k2; x1 += k0 + 5u;
}

// XLA ErfInv32 (Giles)
__device__ __forceinline__ float erfinv_f(float x){
  float w = -log1pf(-x*x);
  float p;
  if (w < 5.f){
    w -= 2.5f;
    p = 2.81022636e-08f;
    p = fmaf(p,w, 3.43273939e-07f);
    p = fmaf(p,w,-3.5233877e-06f);
    p = fmaf(p,w,-4.39150654e-06f);
    p = fmaf(p,w, 0.00021858087f);
    p = fmaf(p,w,-0.00125372503f);
    p = fmaf(p,w,-0.00417768164f);
    p = fmaf(p,w, 0.246640727f);
    p = fmaf(p,w, 1.50140941f);
  } else {
    w = sqrtf(w) - 3.f;
    p = -0.000200214257f;
    p = fmaf(p,w, 0.000100950558f);
    p = fmaf(p,w, 0.00134934322f);
    p = fmaf(p,w,-0.00367342844f);
    p = fmaf(p,w, 0.00573950773f);
    p = fmaf(p,w,-0.0076224613f);
    p = fmaf(p,w, 0.00943887047f);
    p = fmaf(p,w, 1.00167406f);
    p = fmaf(p,w, 2.83297682f);
  }
  return p*x;
}

__device__ __forceinline__ float jax_normal_from_bits(unsigned bits){
  unsigned fb = (bits >> 9) | 0x3f800000u;
  float f = __uint_as_float(fb) - 1.0f;                 // [0,1)
  const float lo = -0.9999999403953552f;                // nextafter(-1,0)
  float u = fmaf(f, 2.0f, lo);
  u = fmaxf(lo, u);
  return 1.4142135623730951f * erfinv_f(u);
}

// psiP[j] = pack(half(cos(theta+tn)), half(sin(phi+pn))), j = k*256+n
__global__ __launch_bounds__(256) void prep_psi(const float* __restrict__ theta,
                                                const float* __restrict__ phi,
                                                unsigned* __restrict__ psiP){
  int j = blockIdx.x*256 + threadIdx.x;  // 0..16383
  unsigned a0=0u, a1=0u; threefry(0u,42u,a0,a1);   // k1 (theta noise)
  unsigned b0=0u, b1=1u; threefry(0u,42u,b0,b1);   // k2 (phi noise)
  unsigned t0=0u, t1=(unsigned)j; threefry(a0,a1,t0,t1);
  unsigned p0=0u, p1=(unsigned)j; threefry(b0,b1,p0,p1);
  float tn = 0.01f * jax_normal_from_bits(t0^t1);
  float pn = 0.01f * jax_normal_from_bits(p0^p1);
  float cr = cosf(theta[j] + tn);
  float ci = sinf(phi[j]   + pn);
  f16x2 pk; pk.x = (f16)cr; pk.y = (f16)ci;
  psiP[j] = __builtin_bit_cast(unsigned, pk);
}

// ======================= weight packing =======================
// WhT4[l][kk][row] = 8 f16 of W_hh[l][row][8kk..8kk+7]  (coalesced per-kk loads)
__global__ __launch_bounds__(256) void pack_wh(const float* __restrict__ Whh,
                                               uint4* __restrict__ WhT4){
  int idx = blockIdx.x*256 + threadIdx.x;     // 0..65535
  int l   = idx >> 15;
  int row = (idx >> 5) & 1023;
  int kk  = idx & 31;
  const float* src = Whh + ((size_t)(l*1024 + row))*256 + kk*8;
  f16x8 tmp;
  #pragma unroll
  for (int j=0;j<8;j++) tmp[j] = (f16)src[j];
  WhT4[l*32768 + kk*1024 + row] = __builtin_bit_cast(uint4, tmp);
}

__global__ __launch_bounds__(256) void pack_wi_bias(const float* __restrict__ Wih,
                                                    const float* __restrict__ bih,
                                                    const float* __restrict__ bhh,
                                                    f16* __restrict__ WiH,
                                                    float* __restrict__ biasS){
  int idx = blockIdx.x*256 + threadIdx.x;     // 0..524287
  WiH[idx] = (f16)Wih[idx];
  if (idx < 2048) biasS[idx] = bih[idx] + bhh[idx];
}

__global__ __launch_bounds__(128) void zero_prog(int* __restrict__ p){
  p[threadIdx.x] = 0;    // prog1[0..63] ++ prog2[0..63] (contiguous, 256B-aligned each)
}

// ======================= quantum phase =======================
__global__ __launch_bounds__(256) void quantum_k(const float* __restrict__ x,
                                                 const unsigned* __restrict__ psiP,
                                                 f16* __restrict__ yq){
  __shared__ float xs[64];
  int m = blockIdx.x;
  int n = threadIdx.x;
  if (n < 64) xs[n] = x[(size_t)m*64 + n];
  __syncthreads();
  float ar=0.f, ai=0.f;
  #pragma unroll 8
  for (int k=0;k<64;k++){
    unsigned p = psiP[k*256 + n];
    f16x2 pk = __builtin_bit_cast(f16x2, p);
    float xv = xs[k];
    ar = fmaf(xv, (float)pk.x, ar);
    ai = fmaf(xv, (float)pk.y, ai);
  }
  yq[(size_t)m*256 + n] = (f16)sqrtf(ar*ar + ai*ai);
}

// ======================= pre-activation GEMM (MFMA f16, layer 1 only) =======================
__global__ __launch_bounds__(256,2) void pre_gemm(const f16* __restrict__ A,
                                                  const f16* __restrict__ W,
                                                  const float* __restrict__ bias,
                                                  f16* __restrict__ out){
  const int m0 = blockIdx.x*64;
  const int n0 = blockIdx.y*512;
  __shared__ f16 As[64*264];
  const int tid = threadIdx.x;
  #pragma unroll
  for (int it=0; it<8; ++it){
    int u = tid + it*256;
    int row = u >> 5, ko = u & 31;
    f16x8 v = *(const f16x8*)(A + (size_t)(m0+row)*256 + ko*8);
    *(f16x8*)(&As[row*264 + ko*8]) = v;
  }
  __syncthreads();
  const int wave = tid >> 6, lane = tid & 63;
  const int n_w = n0 + wave*128;
  const int lr = lane & 15, lk = (lane>>4)*8;
  f32x4 acc[4][8] = {};
  for (int ks=0; ks<8; ++ks){
    f16x8 a[4];
    #pragma unroll
    for (int mt=0; mt<4; ++mt)
      a[mt] = *(const f16x8*)(&As[(mt*16+lr)*264 + ks*32 + lk]);
    #pragma unroll
    for (int nt=0; nt<8; ++nt){
      f16x8 b = *(const f16x8*)(W + (size_t)(n_w + nt*16 + lr)*256 + ks*32 + lk);
      #pragma unroll
      for (int mt=0; mt<4; ++mt)
        acc[mt][nt] = __builtin_amdgcn_mfma_f32_16x16x32_f16(a[mt], b, acc[mt][nt], 0,0,0);
    }
  }
  const int col = lr, rbase = (lane>>4)*4;
  #pragma unroll
  for (int nt=0; nt<8; ++nt){
    float bv = bias[n_w + nt*16 + col];
    #pragma unroll
    for (int mt=0; mt<4; ++mt){
      #pragma unroll
      for (int j=0; j<4; ++j){
        int m = m0 + mt*16 + rbase + j;
        out[(size_t)m*1024 + n_w + nt*16 + col] = (f16)(acc[mt][nt][j] + bv);
      }
    }
  }
}

// ======================= LSTM recurrence =======================
__device__ __forceinline__ float sigm_f(float x){
  x = fminf(fmaxf(x,-30.f),30.f);
  return 1.f/(1.f + __expf(-x));
}
__device__ __forceinline__ float tanh_f(float x){
  x = fminf(fmaxf(x,-15.f),15.f);
  float e = __expf(-2.f*x);
  return (1.f-e)/(1.f+e);
}
__device__ __forceinline__ float dot2f(unsigned w, unsigned h, float acc){
#if __has_builtin(__builtin_amdgcn_fdot2)
  return __builtin_amdgcn_fdot2(__builtin_bit_cast(f16x2,w), __builtin_bit_cast(f16x2,h), acc, false);
#else
  // guarantee the HW dot2 (the cvt+fma fallback is 3x the VALU issue)
  float d;
  asm("v_dot2_f32_f16 %0, %1, %2, %3" : "=v"(d) : "v"(w), "v"(h), "v"(acc));
  return d;
#endif
}

__device__ __forceinline__ f32x4 mfma16(uint4 a, uint4 b, f32x4 c){
  return __builtin_amdgcn_mfma_f32_16x16x32_f16(
      __builtin_bit_cast(f16x8, a), __builtin_bit_cast(f16x8, b), c, 0, 0, 0);
}

// One LSTM layer for one batch on one CU (16 waves, 1 gate row per thread).
// W row split (round-7): 23 uint4 in VGPRs + 5 uint4 in LDS (80 KB) + 4 uint4
// streamed per-step from WhT4 (L2-resident, 64 KB slice per layer). The 9->5 LDS
// cut removes ~900cy/step of per-lane ds_read_b128 pressure; the 4 streamed quads
// ride the (idle) VMEM pipe, or get hoisted to registers if the allocator has room
// -- either outcome beats the LDS path.
// WRITE_ALL=1: producer role — writes h to outh, releases prog_rel every 16 steps.
// CONSUME=1:  consumer role — polls prog_acq before touching each 16-step chunk of preB.
template<int WRITE_ALL, int CONSUME>
__device__ __forceinline__
void lstm_core(const f16* __restrict__ preB,    // [1024][1024] f16 (this batch)
               const uint4* __restrict__ Wh,    // [32][1024] uint4 (this layer)
               f16* __restrict__ outh,          // [1024][256] (this batch) if WRITE_ALL
               f16* __restrict__ hfin_p,        // [256] if !WRITE_ALL
               int* __restrict__ prog_rel,
               int* __restrict__ prog_acq,
               uint4* wlds, uint4* h4, float* gbuf)
{
  const int tid = threadIdx.x;                   // gate row
  uint4 w[23];
  #pragma unroll
  for (int j=0;j<23;++j) w[j] = Wh[j*1024 + tid];
  #pragma unroll
  for (int j=0;j<5;++j)  wlds[j*1024 + tid] = Wh[(23+j)*1024 + tid];
  if (tid < 32) h4[tid] = make_uint4(0u,0u,0u,0u);
  float c = 0.f;

  if (CONSUME){
    if (tid==0){
      while (__hip_atomic_load(prog_acq, __ATOMIC_ACQUIRE, __HIP_MEMORY_SCOPE_AGENT) < 1)
        __builtin_amdgcn_s_sleep(8);
    }
  }
  __syncthreads();

  float pv = (float)preB[tid];
  const int gtype = tid >> 8;                    // 0:i 1:f 2:g 3:o (wave-uniform)
  const uint4* wstr = Wh + 28*1024 + tid;        // streamed quads 28..31

  for (int t=0; t<1024; ++t){
    if (CONSUME){
      if ((t&15)==15 && t<1023){                 // about to prefetch into next chunk
        if (tid==0){
          const int need = ((t+1)>>4) + 1;
          while (__hip_atomic_load(prog_acq, __ATOMIC_ACQUIRE, __HIP_MEMORY_SCOPE_AGENT) < need)
            __builtin_amdgcn_s_sleep(8);
        }
        __syncthreads();
      }
    }
    float pn = (t < 1023) ? (float)preB[(size_t)(t+1)*1024 + tid] : 0.f;
    // issue the 4 streamed W quads early; consumed at the end of the dot chain
    uint4 s0 = wstr[0];
    uint4 s1 = wstr[1024];
    uint4 s2 = wstr[2048];
    uint4 s3 = wstr[3072];
    float a0 = pv, a1 = 0.f;

    // distance-2 rotating prefetch of the h broadcast + the 5 LDS weight quads
    uint4 hb0 = h4[0], hb1 = h4[1];
    uint4 ub0 = wlds[tid], ub1 = wlds[1024 + tid];

    #pragma unroll
    for (int kk=0; kk<23; ++kk){
      uint4 hp = (kk & 1) ? hb1 : hb0;
      if (kk & 1) hb1 = h4[kk+2]; else hb0 = h4[kk+2];   // kk+2 <= 24 < 32
      a0 = dot2f(w[kk].x, hp.x, a0); a1 = dot2f(w[kk].y, hp.y, a1);
      a0 = dot2f(w[kk].z, hp.z, a0); a1 = dot2f(w[kk].w, hp.w, a1);
    }
    #pragma unroll
    for (int j=0; j<5; ++j){
      const int kk = 23 + j;                             // 23..27
      uint4 hp = (kk & 1) ? hb1 : hb0;
      if (kk & 1) hb1 = h4[kk+2]; else hb0 = h4[kk+2];   // kk+2 <= 29 < 32
      uint4 u = (j & 1) ? ub1 : ub0;
      if (j + 2 < 5){ if (j & 1) ub1 = wlds[(j+2)*1024 + tid]; else ub0 = wlds[(j+2)*1024 + tid]; }
      a0 = dot2f(u.x, hp.x, a0); a1 = dot2f(u.y, hp.y, a1);
      a0 = dot2f(u.z, hp.z, a0); a1 = dot2f(u.w, hp.w, a1);
    }
    #pragma unroll
    for (int j=0; j<4; ++j){
      const int kk = 28 + j;                             // 28..31
      uint4 hp = (kk & 1) ? hb1 : hb0;
      if (kk + 2 < 32){ if (kk & 1) hb1 = h4[kk+2]; else hb0 = h4[kk+2]; }
      const uint4 u = (j==0) ? s0 : (j==1) ? s1 : (j==2) ? s2 : s3;
      a0 = dot2f(u.x, hp.x, a0); a1 = dot2f(u.y, hp.y, a1);
      a0 = dot2f(u.z, hp.z, a0); a1 = dot2f(u.w, hp.w, a1);
    }

    {
      const float raw = a0 + a1;
      gbuf[tid] = (gtype == 2) ? tanh_f(raw) : sigm_f(raw);
    }
    __syncthreads();
    if (tid < 256){
      float i_ = gbuf[tid];
      float f_ = gbuf[256+tid];
      float g_ = gbuf[512+tid];
      float o_ = gbuf[768+tid];
      c = fmaf(f_, c, i_*g_);
      float h = o_ * tanh_f(c);
      ((f16*)h4)[tid] = (f16)h;
      if (WRITE_ALL) outh[(size_t)t*256 + tid] = (f16)h;
      else if (t == 1023) hfin_p[tid] = (f16)h;
    }
    __syncthreads();   // drains all waves' loads AND stores (barrier implies full waitcnt)
    if (WRITE_ALL){
      if ((t&15)==15 && tid==0){
        __threadfence();                         // make h chunk agent-visible
        __hip_atomic_store(prog_rel, t+1, __ATOMIC_RELEASE, __HIP_MEMORY_SCOPE_AGENT);
      }
    }
    pv = pn;
  }
}

// Layer-2 input GEMM role: per 16-step chunk, pre2[t][gate] = h1[t] @ W_ih2^T + bias2.
// M=16 (timesteps), N=1024 (gates), K=256. Same MFMA shape, same K-accumulate order,
// same f16 rounding as pre_gemm -> bit-identical to the previous two-pass version.
// B fragments are read straight from WiH layer 2 (8 contiguous f16 per lane), no
// repack needed. pre2b ALIASES pre1: chunk c (rows 16c..16c+15) is written only
// after prog1 >= 16(c+1), i.e. after the L1 LSTM has loaded rows <= 16c+16 (its
// loads drain at the end-of-step barrier BEFORE the release) and it never re-reads
// them -> WAR-safe.
__device__ __forceinline__
void gemm_role(const f16* __restrict__ h1b,     // [1024][256] this batch
               const f16* __restrict__ W2,      // [1024][256] f16 (layer-2 W_ih)
               const float* __restrict__ bias2, // [1024]
               f16* __restrict__ pre2b,         // [1024][1024] this batch (aliases pre1)
               int* __restrict__ prog1b,
               int* __restrict__ prog2b)
{
  const int tid  = threadIdx.x;
  const int w    = tid >> 6, lane = tid & 63;
  const int lr   = lane & 15, lq = lane >> 4;
  for (int cidx=0; cidx<64; ++cidx){
    if (tid==0){
      while (__hip_atomic_load(prog1b, __ATOMIC_ACQUIRE, __HIP_MEMORY_SCOPE_AGENT) < 16*(cidx+1))
        __builtin_amdgcn_s_sleep(8);
    }
    __syncthreads();
    const int t0 = cidx*16;
    const f16* Ab = h1b + ((size_t)(t0 + lr))*256 + lq*8;
    uint4 af[8];
    #pragma unroll
    for (int ks=0; ks<8; ++ks) af[ks] = *(const uint4*)(Ab + ks*32);
    #pragma unroll
    for (int nt=0; nt<4; ++nt){
      f32x4 acc = {0.f,0.f,0.f,0.f};
      const int gate = w*64 + nt*16 + lr;
      const f16* Bb = W2 + (size_t)gate*256 + lq*8;
      #pragma unroll
      for (int ks=0; ks<8; ++ks){
        const uint4 bf = *(const uint4*)(Bb + ks*32);
        acc = mfma16(af[ks], bf, acc);
      }
      const float bv = bias2[gate];
      #pragma unroll
      for (int j=0; j<4; ++j){
        const int t = t0 + lq*4 + j;
        pre2b[(size_t)t*1024 + gate] = (f16)(acc[j] + bv);
      }
    }
    asm volatile("s_waitcnt vmcnt(0)" ::: "memory");
    __syncthreads();
    if (tid==0){
      __threadfence();
      __hip_atomic_store(prog2b, cidx+1, __ATOMIC_RELEASE, __HIP_MEMORY_SCOPE_AGENT);
    }
  }
}

// ======================= fused two-layer pipeline =======================
// 192 blocks (~86 KB LDS, 1024 thr -> 1 block/CU; 192 <= 256 so all co-resident):
//   blocks   0..63  : layer-1 LSTM (producer of h1)
//   blocks  64..127 : layer-2 input GEMM (h1 -> pre2), 16-step chunks
//   blocks 128..191 : layer-2 LSTM (consumer of pre2)
// Dataflow is strictly one-directional (producers never wait on consumers),
// progress counters are monotone (no slot reuse) -> deadlock/livelock-free
// even under arbitrary dispatch order. Blocks b, b+64, b+128 land on the same
// XCD (same index mod 8) so chunk handoffs stay in one L2.
__global__ __launch_bounds__(1024)
void pipeline_k(const f16* __restrict__ pre1,
                const uint4* __restrict__ WhT4,
                const f16* __restrict__ W2,      // WiH + 262144
                const float* __restrict__ biasS,
                f16* __restrict__ h1,
                f16* __restrict__ pre2,          // == pre1 (alias)
                f16* __restrict__ hfin,
                int* __restrict__ prog1,
                int* __restrict__ prog2)
{
  __shared__ __align__(16) uint4 wlds[5*1024];   // 80 KB
  __shared__ __align__(16) uint4 h4[32];
  __shared__ float gbuf[1024];
  const int bid = blockIdx.x;
  if (bid < 64){
    const int b = bid;
    lstm_core<1,0>(pre1 + (size_t)b*1024*1024, WhT4,
                   h1 + (size_t)b*1024*256, nullptr,
                   prog1 + b, nullptr, wlds, h4, gbuf);
  } else if (bid < 128){
    const int b = bid - 64;
    gemm_role(h1 + (size_t)b*1024*256, W2, biasS + 1024,
              pre2 + (size_t)b*1024*1024, prog1 + b, prog2 + b);
  } else {
    const int b = bid - 128;
    lstm_core<0,1>(pre2 + (size_t)b*1024*1024, WhT4 + 32768,
                   nullptr, hfin + b*256,
                   nullptr, prog2 + b, wlds, h4, gbuf);
  }
}

// ======================= final FC =======================
__global__ __launch_bounds__(64) void fc_k(const f16* __restrict__ hfin,
                                           const float* __restrict__ Wfc,
                                           const float* __restrict__ bfc,
                                           float* __restrict__ out){
  int b = blockIdx.x, k = threadIdx.x;
  float a = 0.f;
  #pragma unroll
  for (int j=0;j<4;j++){
    int idx = k + 64*j;
    a += (float)hfin[b*256 + idx] * Wfc[idx];
  }
  #pragma unroll
  for (int off=32; off; off>>=1) a += __shfl_down(a, off);
  if (k==0) out[b] = a + bfc[0];
}

// ======================= launch =======================
extern "C" void kernel_launch(void* const* d_in, const int* in_sizes, int n_in,
                              void* d_out, int out_size, void* d_ws, size_t ws_size,
                              hipStream_t stream) {
  const float* x     = (const float*)d_in[0];
  const float* theta = (const float*)d_in[1];
  const float* phi   = (const float*)d_in[2];
  const float* Wih   = (const float*)d_in[3];
  const float* Whh   = (const float*)d_in[4];
  const float* bih   = (const float*)d_in[5];
  const float* bhh   = (const float*)d_in[6];
  const float* Wfc   = (const float*)d_in[7];
  const float* bfc   = (const float*)d_in[8];
  float* out = (float*)d_out;

  char* ws = (char*)d_ws;
  size_t off = 0;
  auto take = [&](size_t bytes){ size_t r = off; off += (bytes + 255) & ~(size_t)255; return r; };
  // Total ~203.6 MB (round-0's proven 203.5 MB + 512 B of progress counters).
  f16*      pre1  = (f16*)     (ws + take((size_t)M_*1024*2));   // 134 MB
  f16*      pre2  = pre1;                                        // ALIAS (WAR-safe, see gemm_role)
  f16*      yq    = (f16*)     (ws + take((size_t)M_*256*2));    // 33.5 MB
  f16*      h1    = (f16*)     (ws + take((size_t)M_*256*2));    // 33.5 MB
  unsigned* psiP  = (unsigned*)(ws + take((size_t)16384*4));
  uint4*    WhT4  = (uint4*)   (ws + take((size_t)2*32768*16));  // 1 MB
  f16*      WiH   = (f16*)     (ws + take((size_t)2*262144*2));  // 1 MB
  float*    biasS = (float*)   (ws + take((size_t)2048*4));
  f16*      hfin  = (f16*)     (ws + take((size_t)64*256*2));
  int*      prog1 = (int*)     (ws + take((size_t)64*4));
  int*      prog2 = (int*)     (ws + take((size_t)64*4));        // contiguous after prog1

  zero_prog   <<<1,    128, 0, stream>>>(prog1);
  prep_psi    <<<64,   256, 0, stream>>>(theta, phi, psiP);
  pack_wh     <<<256,  256, 0, stream>>>(Whh, WhT4);
  pack_wi_bias<<<2048, 256, 0, stream>>>(Wih, bih, bhh, WiH, biasS);
  quantum_k   <<<65536,256, 0, stream>>>(x, psiP, yq);

  dim3 gg(1024, 2);
  pre_gemm <<<gg, 256, 0, stream>>>(yq, WiH, biasS, pre1);   // layer-1 input GEMM

  pipeline_k <<<192, 1024, 0, stream>>>(pre1, WhT4, WiH + 262144, biasS,
                                        h1, pre2, hfin, prog1, prog2);

  fc_k <<<64, 64, 0, stream>>>(hfin, Wfc, bfc, out);
}

// Round 8
// 2597.434 us; speedup vs baseline: 5.3352x; 1.0020x over previous
//
#include <hip/hip_runtime.h>

typedef _Float16 f16;
typedef _Float16 f16x2 __attribute__((ext_vector_type(2)));
typedef _Float16 f16x8 __attribute__((ext_vector_type(8)));
typedef float f32x4 __attribute__((ext_vector_type(4)));

#define B_ 64
#define S_ 1024
#define I_ 64
#define H_ 256
#define G_ 1024      // 4*H
#define M_ 65536     // B*S

// ======================= Threefry-2x32-20 (JAX) =======================
__device__ __forceinline__ unsigned rotl32(unsigned x, int r){ return (x<<r)|(x>>(32-r)); }

__device__ __forceinline__ void threefry(unsigned k0, unsigned k1, unsigned& x0, unsigned& x1){
  unsigned k2 = k0 ^ k1 ^ 0x1BD11BDAu;
  x0 += k0; x1 += k1;
  x0 += x1; x1 = rotl32(x1,13); x1 ^= x0;
  x0 += x1; x1 = rotl32(x1,15); x1 ^= x0;
  x0 += x1; x1 = rotl32(x1,26); x1 ^= x0;
  x0 += x1; x1 = rotl32(x1, 6); x1 ^= x0;
  x0 += k1; x1 += k2 + 1u;
  x0 += x1; x1 = rotl32(x1,17); x1 ^= x0;
  x0 += x1; x1 = rotl32(x1,29); x1 ^= x0;
  x0 += x1; x1 = rotl32(x1,16); x1 ^= x0;
  x0 += x1; x1 = rotl32(x1,24); x1 ^= x0;
  x0 += k2; x1 += k0 + 2u;
  x0 += x1; x1 = rotl32(x1,13); x1 ^= x0;
  x0 += x1; x1 = rotl32(x1,15); x1 ^= x0;
  x0 += x1; x1 = rotl32(x1,26); x1 ^= x0;
  x0 += x1; x1 = rotl32(x1, 6); x1 ^= x0;
  x0 += k0; x1 += k1 + 3u;
  x0 += x1; x1 = rotl32(x1,17); x1 ^= x0;
  x0 += x1; x1 = rotl32(x1,29); x1 ^= x0;
  x0 += x1; x1 = rotl32(x1,16); x1 ^= x0;
  x0 += x1; x1 = rotl32(x1,24); x1 ^= x0;
  x0 += k1; x1 += k2 + 4u;
  x0 += x1; x1 = rotl32(x1,13); x1 ^= x0;
  x0 += x1; x1 = rotl32(x1,15); x1 ^= x0;
  x0 += x1; x1 = rotl32(x1,26); x1 ^= x0;
  x0 += x1; x1 = rotl32(x1, 6); x1 ^= x0;
  x0 += k2; x1 += k0 + 5u;
}

// XLA ErfInv32 (Giles)
__device__ __forceinline__ float erfinv_f(float x){
  float w = -log1pf(-x*x);
  float p;
  if (w < 5.f){
    w -= 2.5f;
    p = 2.81022636e-08f;
    p = fmaf(p,w, 3.43273939e-07f);
    p = fmaf(p,w,-3.5233877e-06f);
    p = fmaf(p,w,-4.39150654e-06f);
    p = fmaf(p,w, 0.00021858087f);
    p = fmaf(p,w,-0.00125372503f);
    p = fmaf(p,w,-0.00417768164f);
    p = fmaf(p,w, 0.246640727f);
    p = fmaf(p,w, 1.50140941f);
  } else {
    w = sqrtf(w) - 3.f;
    p = -0.000200214257f;
    p = fmaf(p,w, 0.000100950558f);
    p = fmaf(p,w, 0.00134934322f);
    p = fmaf(p,w,-0.00367342844f);
    p = fmaf(p,w, 0.00573950773f);
    p = fmaf(p,w,-0.0076224613f);
    p = fmaf(p,w, 0.00943887047f);
    p = fmaf(p,w, 1.00167406f);
    p = fmaf(p,w, 2.83297682f);
  }
  return p*x;
}

__device__ __forceinline__ float jax_normal_from_bits(unsigned bits){
  unsigned fb = (bits >> 9) | 0x3f800000u;
  float f = __uint_as_float(fb) - 1.0f;                 // [0,1)
  const float lo = -0.9999999403953552f;                // nextafter(-1,0)
  float u = fmaf(f, 2.0f, lo);
  u = fmaxf(lo, u);
  return 1.4142135623730951f * erfinv_f(u);
}

// psiP[j] = pack(half(cos(theta+tn)), half(sin(phi+pn))), j = k*256+n
__global__ __launch_bounds__(256) void prep_psi(const float* __restrict__ theta,
                                                const float* __restrict__ phi,
                                                unsigned* __restrict__ psiP){
  int j = blockIdx.x*256 + threadIdx.x;  // 0..16383
  unsigned a0=0u, a1=0u; threefry(0u,42u,a0,a1);   // k1 (theta noise)
  unsigned b0=0u, b1=1u; threefry(0u,42u,b0,b1);   // k2 (phi noise)
  unsigned t0=0u, t1=(unsigned)j; threefry(a0,a1,t0,t1);
  unsigned p0=0u, p1=(unsigned)j; threefry(b0,b1,p0,p1);
  float tn = 0.01f * jax_normal_from_bits(t0^t1);
  float pn = 0.01f * jax_normal_from_bits(p0^p1);
  float cr = cosf(theta[j] + tn);
  float ci = sinf(phi[j]   + pn);
  f16x2 pk; pk.x = (f16)cr; pk.y = (f16)ci;
  psiP[j] = __builtin_bit_cast(unsigned, pk);
}

// ======================= weight packing =======================
// WhT4[l][kk][row] = 8 f16 of W_hh[l][row][8kk..8kk+7]  (coalesced per-kk loads)
__global__ __launch_bounds__(256) void pack_wh(const float* __restrict__ Whh,
                                               uint4* __restrict__ WhT4){
  int idx = blockIdx.x*256 + threadIdx.x;     // 0..65535
  int l   = idx >> 15;
  int row = (idx >> 5) & 1023;
  int kk  = idx & 31;
  const float* src = Whh + ((size_t)(l*1024 + row))*256 + kk*8;
  f16x8 tmp;
  #pragma unroll
  for (int j=0;j<8;j++) tmp[j] = (f16)src[j];
  WhT4[l*32768 + kk*1024 + row] = __builtin_bit_cast(uint4, tmp);
}

__global__ __launch_bounds__(256) void pack_wi_bias(const float* __restrict__ Wih,
                                                    const float* __restrict__ bih,
                                                    const float* __restrict__ bhh,
                                                    f16* __restrict__ WiH,
                                                    float* __restrict__ biasS){
  int idx = blockIdx.x*256 + threadIdx.x;     // 0..524287
  WiH[idx] = (f16)Wih[idx];
  if (idx < 2048) biasS[idx] = bih[idx] + bhh[idx];
}

__global__ __launch_bounds__(128) void zero_prog(int* __restrict__ p){
  p[threadIdx.x] = 0;    // prog1[0..63] ++ prog2[0..63] (contiguous, 256B-aligned each)
}

// ======================= quantum phase =======================
__global__ __launch_bounds__(256) void quantum_k(const float* __restrict__ x,
                                                 const unsigned* __restrict__ psiP,
                                                 f16* __restrict__ yq){
  __shared__ float xs[64];
  int m = blockIdx.x;
  int n = threadIdx.x;
  if (n < 64) xs[n] = x[(size_t)m*64 + n];
  __syncthreads();
  float ar=0.f, ai=0.f;
  #pragma unroll 8
  for (int k=0;k<64;k++){
    unsigned p = psiP[k*256 + n];
    f16x2 pk = __builtin_bit_cast(f16x2, p);
    float xv = xs[k];
    ar = fmaf(xv, (float)pk.x, ar);
    ai = fmaf(xv, (float)pk.y, ai);
  }
  yq[(size_t)m*256 + n] = (f16)sqrtf(ar*ar + ai*ai);
}

// ======================= pre-activation GEMM (MFMA f16, layer 1 only) =======================
__global__ __launch_bounds__(256,2) void pre_gemm(const f16* __restrict__ A,
                                                  const f16* __restrict__ W,
                                                  const float* __restrict__ bias,
                                                  f16* __restrict__ out){
  const int m0 = blockIdx.x*64;
  const int n0 = blockIdx.y*512;
  __shared__ f16 As[64*264];
  const int tid = threadIdx.x;
  #pragma unroll
  for (int it=0; it<8; ++it){
    int u = tid + it*256;
    int row = u >> 5, ko = u & 31;
    f16x8 v = *(const f16x8*)(A + (size_t)(m0+row)*256 + ko*8);
    *(f16x8*)(&As[row*264 + ko*8]) = v;
  }
  __syncthreads();
  const int wave = tid >> 6, lane = tid & 63;
  const int n_w = n0 + wave*128;
  const int lr = lane & 15, lk = (lane>>4)*8;
  f32x4 acc[4][8] = {};
  for (int ks=0; ks<8; ++ks){
    f16x8 a[4];
    #pragma unroll
    for (int mt=0; mt<4; ++mt)
      a[mt] = *(const f16x8*)(&As[(mt*16+lr)*264 + ks*32 + lk]);
    #pragma unroll
    for (int nt=0; nt<8; ++nt){
      f16x8 b = *(const f16x8*)(W + (size_t)(n_w + nt*16 + lr)*256 + ks*32 + lk);
      #pragma unroll
      for (int mt=0; mt<4; ++mt)
        acc[mt][nt] = __builtin_amdgcn_mfma_f32_16x16x32_f16(a[mt], b, acc[mt][nt], 0,0,0);
    }
  }
  const int col = lr, rbase = (lane>>4)*4;
  #pragma unroll
  for (int nt=0; nt<8; ++nt){
    float bv = bias[n_w + nt*16 + col];
    #pragma unroll
    for (int mt=0; mt<4; ++mt){
      #pragma unroll
      for (int j=0; j<4; ++j){
        int m = m0 + mt*16 + rbase + j;
        out[(size_t)m*1024 + n_w + nt*16 + col] = (f16)(acc[mt][nt][j] + bv);
      }
    }
  }
}

// ======================= LSTM recurrence =======================
__device__ __forceinline__ float sigm_f(float x){
  x = fminf(fmaxf(x,-30.f),30.f);
  return 1.f/(1.f + __expf(-x));
}
__device__ __forceinline__ float tanh_f(float x){
  x = fminf(fmaxf(x,-15.f),15.f);
  float e = __expf(-2.f*x);
  return (1.f-e)/(1.f+e);
}
__device__ __forceinline__ float dot2f(unsigned w, unsigned h, float acc){
#if __has_builtin(__builtin_amdgcn_fdot2)
  return __builtin_amdgcn_fdot2(__builtin_bit_cast(f16x2,w), __builtin_bit_cast(f16x2,h), acc, false);
#else
  // guarantee the HW dot2 (the cvt+fma fallback is 3x the VALU issue)
  float d;
  asm("v_dot2_f32_f16 %0, %1, %2, %3" : "=v"(d) : "v"(w), "v"(h), "v"(acc));
  return d;
#endif
}

__device__ __forceinline__ f32x4 mfma16(uint4 a, uint4 b, f32x4 c){
  return __builtin_amdgcn_mfma_f32_16x16x32_f16(
      __builtin_bit_cast(f16x8, a), __builtin_bit_cast(f16x8, b), c, 0, 0, 0);
}

// One LSTM layer for one batch on one CU (16 waves, 1 gate row per thread).
// W row split: 23 uint4 in VGPRs + 5 uint4 in LDS (80 KB) + 4 uint4 streamed
// per-step from WhT4 (L2-resident).
// ROUND-8: __launch_bounds__(1024, 4) on pipeline_k grants the 128-VGPR/wave
// budget (LDS already caps us at 16 waves/CU = 4 waves/EU). Without it the
// allocator targeted 8 waves/EU -> 64 VGPR, pushing w[23] (92 regs) into AGPRs
// and paying ~92 v_accvgpr_read VALU ops per thread per step (VGPR_Count=64 in
// every profile since round 0 is the smoking gun).
template<int WRITE_ALL, int CONSUME>
__device__ __forceinline__
void lstm_core(const f16* __restrict__ preB,    // [1024][1024] f16 (this batch)
               const uint4* __restrict__ Wh,    // [32][1024] uint4 (this layer)
               f16* __restrict__ outh,          // [1024][256] (this batch) if WRITE_ALL
               f16* __restrict__ hfin_p,        // [256] if !WRITE_ALL
               int* __restrict__ prog_rel,
               int* __restrict__ prog_acq,
               uint4* wlds, uint4* h4, float* gbuf)
{
  const int tid = threadIdx.x;                   // gate row
  uint4 w[23];
  #pragma unroll
  for (int j=0;j<23;++j) w[j] = Wh[j*1024 + tid];
  #pragma unroll
  for (int j=0;j<5;++j)  wlds[j*1024 + tid] = Wh[(23+j)*1024 + tid];
  if (tid < 32) h4[tid] = make_uint4(0u,0u,0u,0u);
  float c = 0.f;

  if (CONSUME){
    if (tid==0){
      while (__hip_atomic_load(prog_acq, __ATOMIC_ACQUIRE, __HIP_MEMORY_SCOPE_AGENT) < 1)
        __builtin_amdgcn_s_sleep(8);
    }
  }
  __syncthreads();

  float pv = (float)preB[tid];
  const int gtype = tid >> 8;                    // 0:i 1:f 2:g 3:o (wave-uniform)
  const uint4* wstr = Wh + 28*1024 + tid;        // streamed quads 28..31

  for (int t=0; t<1024; ++t){
    if (CONSUME){
      if ((t&15)==15 && t<1023){                 // about to prefetch into next chunk
        if (tid==0){
          const int need = ((t+1)>>4) + 1;
          while (__hip_atomic_load(prog_acq, __ATOMIC_ACQUIRE, __HIP_MEMORY_SCOPE_AGENT) < need)
            __builtin_amdgcn_s_sleep(8);
        }
        __syncthreads();
      }
    }
    float pn = (t < 1023) ? (float)preB[(size_t)(t+1)*1024 + tid] : 0.f;
    // issue the 4 streamed W quads early; consumed at the end of the dot chain
    uint4 s0 = wstr[0];
    uint4 s1 = wstr[1024];
    uint4 s2 = wstr[2048];
    uint4 s3 = wstr[3072];
    float a0 = pv, a1 = 0.f;

    // distance-2 rotating prefetch of the h broadcast + the 5 LDS weight quads
    uint4 hb0 = h4[0], hb1 = h4[1];
    uint4 ub0 = wlds[tid], ub1 = wlds[1024 + tid];

    #pragma unroll
    for (int kk=0; kk<23; ++kk){
      uint4 hp = (kk & 1) ? hb1 : hb0;
      if (kk & 1) hb1 = h4[kk+2]; else hb0 = h4[kk+2];   // kk+2 <= 24 < 32
      a0 = dot2f(w[kk].x, hp.x, a0); a1 = dot2f(w[kk].y, hp.y, a1);
      a0 = dot2f(w[kk].z, hp.z, a0); a1 = dot2f(w[kk].w, hp.w, a1);
    }
    #pragma unroll
    for (int j=0; j<5; ++j){
      const int kk = 23 + j;                             // 23..27
      uint4 hp = (kk & 1) ? hb1 : hb0;
      if (kk & 1) hb1 = h4[kk+2]; else hb0 = h4[kk+2];   // kk+2 <= 29 < 32
      uint4 u = (j & 1) ? ub1 : ub0;
      if (j + 2 < 5){ if (j & 1) ub1 = wlds[(j+2)*1024 + tid]; else ub0 = wlds[(j+2)*1024 + tid]; }
      a0 = dot2f(u.x, hp.x, a0); a1 = dot2f(u.y, hp.y, a1);
      a0 = dot2f(u.z, hp.z, a0); a1 = dot2f(u.w, hp.w, a1);
    }
    #pragma unroll
    for (int j=0; j<4; ++j){
      const int kk = 28 + j;                             // 28..31
      uint4 hp = (kk & 1) ? hb1 : hb0;
      if (kk + 2 < 32){ if (kk & 1) hb1 = h4[kk+2]; else hb0 = h4[kk+2]; }
      const uint4 u = (j==0) ? s0 : (j==1) ? s1 : (j==2) ? s2 : s3;
      a0 = dot2f(u.x, hp.x, a0); a1 = dot2f(u.y, hp.y, a1);
      a0 = dot2f(u.z, hp.z, a0); a1 = dot2f(u.w, hp.w, a1);
    }

    {
      const float raw = a0 + a1;
      gbuf[tid] = (gtype == 2) ? tanh_f(raw) : sigm_f(raw);
    }
    __syncthreads();
    if (tid < 256){
      float i_ = gbuf[tid];
      float f_ = gbuf[256+tid];
      float g_ = gbuf[512+tid];
      float o_ = gbuf[768+tid];
      c = fmaf(f_, c, i_*g_);
      float h = o_ * tanh_f(c);
      ((f16*)h4)[tid] = (f16)h;
      if (WRITE_ALL) outh[(size_t)t*256 + tid] = (f16)h;
      else if (t == 1023) hfin_p[tid] = (f16)h;
    }
    __syncthreads();   // drains all waves' loads AND stores (barrier implies full waitcnt)
    if (WRITE_ALL){
      if ((t&15)==15 && tid==0){
        __threadfence();                         // make h chunk agent-visible
        __hip_atomic_store(prog_rel, t+1, __ATOMIC_RELEASE, __HIP_MEMORY_SCOPE_AGENT);
      }
    }
    pv = pn;
  }
}

// Layer-2 input GEMM role: per 16-step chunk, pre2[t][gate] = h1[t] @ W_ih2^T + bias2.
// M=16 (timesteps), N=1024 (gates), K=256. Same MFMA shape, same K-accumulate order,
// same f16 rounding as pre_gemm -> bit-identical to the previous two-pass version.
// B fragments are read straight from WiH layer 2 (8 contiguous f16 per lane), no
// repack needed. pre2b ALIASES pre1: chunk c (rows 16c..16c+15) is written only
// after prog1 >= 16(c+1), i.e. after the L1 LSTM has loaded rows <= 16c+16 (its
// loads drain at the end-of-step barrier BEFORE the release) and it never re-reads
// them -> WAR-safe.
__device__ __forceinline__
void gemm_role(const f16* __restrict__ h1b,     // [1024][256] this batch
               const f16* __restrict__ W2,      // [1024][256] f16 (layer-2 W_ih)
               const float* __restrict__ bias2, // [1024]
               f16* __restrict__ pre2b,         // [1024][1024] this batch (aliases pre1)
               int* __restrict__ prog1b,
               int* __restrict__ prog2b)
{
  const int tid  = threadIdx.x;
  const int w    = tid >> 6, lane = tid & 63;
  const int lr   = lane & 15, lq = lane >> 4;
  for (int cidx=0; cidx<64; ++cidx){
    if (tid==0){
      while (__hip_atomic_load(prog1b, __ATOMIC_ACQUIRE, __HIP_MEMORY_SCOPE_AGENT) < 16*(cidx+1))
        __builtin_amdgcn_s_sleep(8);
    }
    __syncthreads();
    const int t0 = cidx*16;
    const f16* Ab = h1b + ((size_t)(t0 + lr))*256 + lq*8;
    uint4 af[8];
    #pragma unroll
    for (int ks=0; ks<8; ++ks) af[ks] = *(const uint4*)(Ab + ks*32);
    #pragma unroll
    for (int nt=0; nt<4; ++nt){
      f32x4 acc = {0.f,0.f,0.f,0.f};
      const int gate = w*64 + nt*16 + lr;
      const f16* Bb = W2 + (size_t)gate*256 + lq*8;
      #pragma unroll
      for (int ks=0; ks<8; ++ks){
        const uint4 bf = *(const uint4*)(Bb + ks*32);
        acc = mfma16(af[ks], bf, acc);
      }
      const float bv = bias2[gate];
      #pragma unroll
      for (int j=0; j<4; ++j){
        const int t = t0 + lq*4 + j;
        pre2b[(size_t)t*1024 + gate] = (f16)(acc[j] + bv);
      }
    }
    asm volatile("s_waitcnt vmcnt(0)" ::: "memory");
    __syncthreads();
    if (tid==0){
      __threadfence();
      __hip_atomic_store(prog2b, cidx+1, __ATOMIC_RELEASE, __HIP_MEMORY_SCOPE_AGENT);
    }
  }
}

// ======================= fused two-layer pipeline =======================
// 192 blocks (~86 KB LDS, 1024 thr -> 1 block/CU; 192 <= 256 so all co-resident):
//   blocks   0..63  : layer-1 LSTM (producer of h1)
//   blocks  64..127 : layer-2 input GEMM (h1 -> pre2), 16-step chunks
//   blocks 128..191 : layer-2 LSTM (consumer of pre2)
// Dataflow is strictly one-directional (producers never wait on consumers),
// progress counters are monotone (no slot reuse) -> deadlock/livelock-free
// even under arbitrary dispatch order. Blocks b, b+64, b+128 land on the same
// XCD (same index mod 8) so chunk handoffs stay in one L2.
// __launch_bounds__(1024, 4): 4 waves/EU min -> 128-VGPR budget (see lstm_core).
__global__ __launch_bounds__(1024, 4)
void pipeline_k(const f16* __restrict__ pre1,
                const uint4* __restrict__ WhT4,
                const f16* __restrict__ W2,      // WiH + 262144
                const float* __restrict__ biasS,
                f16* __restrict__ h1,
                f16* __restrict__ pre2,          // == pre1 (alias)
                f16* __restrict__ hfin,
                int* __restrict__ prog1,
                int* __restrict__ prog2)
{
  __shared__ __align__(16) uint4 wlds[5*1024];   // 80 KB
  __shared__ __align__(16) uint4 h4[32];
  __shared__ float gbuf[1024];
  const int bid = blockIdx.x;
  if (bid < 64){
    const int b = bid;
    lstm_core<1,0>(pre1 + (size_t)b*1024*1024, WhT4,
                   h1 + (size_t)b*1024*256, nullptr,
                   prog1 + b, nullptr, wlds, h4, gbuf);
  } else if (bid < 128){
    const int b = bid - 64;
    gemm_role(h1 + (size_t)b*1024*256, W2, biasS + 1024,
              pre2 + (size_t)b*1024*1024, prog1 + b, prog2 + b);
  } else {
    const int b = bid - 128;
    lstm_core<0,1>(pre2 + (size_t)b*1024*1024, WhT4 + 32768,
                   nullptr, hfin + b*256,
                   nullptr, prog2 + b, wlds, h4, gbuf);
  }
}

// ======================= final FC =======================
__global__ __launch_bounds__(64) void fc_k(const f16* __restrict__ hfin,
                                           const float* __restrict__ Wfc,
                                           const float* __restrict__ bfc,
                                           float* __restrict__ out){
  int b = blockIdx.x, k = threadIdx.x;
  float a = 0.f;
  #pragma unroll
  for (int j=0;j<4;j++){
    int idx = k + 64*j;
    a += (float)hfin[b*256 + idx] * Wfc[idx];
  }
  #pragma unroll
  for (int off=32; off; off>>=1) a += __shfl_down(a, off);
  if (k==0) out[b] = a + bfc[0];
}

// ======================= launch =======================
extern "C" void kernel_launch(void* const* d_in, const int* in_sizes, int n_in,
                              void* d_out, int out_size, void* d_ws, size_t ws_size,
                              hipStream_t stream) {
  const float* x     = (const float*)d_in[0];
  const float* theta = (const float*)d_in[1];
  const float* phi   = (const float*)d_in[2];
  const float* Wih   = (const float*)d_in[3];
  const float* Whh   = (const float*)d_in[4];
  const float* bih   = (const float*)d_in[5];
  const float* bhh   = (const float*)d_in[6];
  const float* Wfc   = (const float*)d_in[7];
  const float* bfc   = (const float*)d_in[8];
  float* out = (float*)d_out;

  char* ws = (char*)d_ws;
  size_t off = 0;
  auto take = [&](size_t bytes){ size_t r = off; off += (bytes + 255) & ~(size_t)255; return r; };
  // Total ~203.6 MB (round-0's proven 203.5 MB + 512 B of progress counters).
  f16*      pre1  = (f16*)     (ws + take((size_t)M_*1024*2));   // 134 MB
  f16*      pre2  = pre1;                                        // ALIAS (WAR-safe, see gemm_role)
  f16*      yq    = (f16*)     (ws + take((size_t)M_*256*2));    // 33.5 MB
  f16*      h1    = (f16*)     (ws + take((size_t)M_*256*2));    // 33.5 MB
  unsigned* psiP  = (unsigned*)(ws + take((size_t)16384*4));
  uint4*    WhT4  = (uint4*)   (ws + take((size_t)2*32768*16));  // 1 MB
  f16*      WiH   = (f16*)     (ws + take((size_t)2*262144*2));  // 1 MB
  float*    biasS = (float*)   (ws + take((size_t)2048*4));
  f16*      hfin  = (f16*)     (ws + take((size_t)64*256*2));
  int*      prog1 = (int*)     (ws + take((size_t)64*4));
  int*      prog2 = (int*)     (ws + take((size_t)64*4));        // contiguous after prog1

  zero_prog   <<<1,    128, 0, stream>>>(prog1);
  prep_psi    <<<64,   256, 0, stream>>>(theta, phi, psiP);
  pack_wh     <<<256,  256, 0, stream>>>(Whh, WhT4);
  pack_wi_bias<<<2048, 256, 0, stream>>>(Wih, bih, bhh, WiH, biasS);
  quantum_k   <<<65536,256, 0, stream>>>(x, psiP, yq);

  dim3 gg(1024, 2);
  pre_gemm <<<gg, 256, 0, stream>>>(yq, WiH, biasS, pre1);   // layer-1 input GEMM

  pipeline_k <<<192, 1024, 0, stream>>>(pre1, WhT4, WiH + 262144, biasS,
                                        h1, pre2, hfin, prog1, prog2);

  fc_k <<<64, 64, 0, stream>>>(hfin, Wfc, bfc, out);
}